// Round 21
// baseline (411.785 us; speedup 1.0000x reference)
//
#include <hip/hip_runtime.h>
#include <math.h>

typedef __bf16 bf16x8 __attribute__((ext_vector_type(8)));
typedef __bf16 bf16x4 __attribute__((ext_vector_type(4)));
typedef float  f32x4  __attribute__((ext_vector_type(4)));

constexpr int Bc = 64, Sc = 1024, Dc = 768;
constexpr int ISc = 307, IDc = 230;
constexpr int ISp = 384, IDp = 256;   // padded: every GEMM M,N %128==0, K %64==0

static __device__ __forceinline__ float bf2f(unsigned short u) {
    return __builtin_bit_cast(float, (unsigned)u << 16);
}
// tanh-form GELU via exp2/rcp (trans pipe); |delta| vs erf-gelu ~3e-3 (safe).
static __device__ __forceinline__ float gelu_f(float v) {
    const float y = v * (0.7978845608f + 0.0356774081f * v * v);
    const float e = __builtin_amdgcn_exp2f(y * 2.8853900818f);
    return v * e * __builtin_amdgcn_rcpf(e + 1.0f);
}

// async global->LDS, 16B/lane, linear LDS dest (wave-uniform base + lane*16)
static __device__ __forceinline__ void gload16(const void* g, void* l) {
    __builtin_amdgcn_global_load_lds(
        (const __attribute__((address_space(1))) void*)g,
        (__attribute__((address_space(3))) void*)l, 16, 0, 0);
}

// ---------------- fused front kernel: weight cvt + LN1-transpose ----------
constexpr int CH0 = 10 * ISp * (Sc  / 8);
constexpr int CH1 = 10 * Sc  * (ISp / 8);
constexpr int CH2 = 10 * IDp * (Dc  / 8);
constexpr int CH3 = 10 * Dc  * (IDp / 8);
constexpr int CB0 = CH0, CB1 = CB0 + CH1, CB2 = CB1 + CH2, CB3 = CB2 + CH3;
constexpr int CVT_BLK = CB3 / 256;          // 5760 exactly
constexpr int LN1_BLK = (Sc / 32) * Bc;     // 2048

__device__ __forceinline__ void cvt_one(
    const float* __restrict__ in, __bf16* __restrict__ out,
    int inrows, int outrows, int incols, int outcols, int c)
{
    const int cpr  = outcols >> 3;
    const int perT = outrows * cpr;
    const int t    = c / perT;
    const int rem  = c - t * perT;
    const int r    = rem / cpr;
    const int cc   = (rem - r * cpr) * 8;
    bf16x8 o;
    if (r < inrows) {
        const float* src = in + ((long)t * inrows + r) * incols + cc;
        #pragma unroll
        for (int e = 0; e < 8; e++)
            o[e] = (cc + e < incols) ? (__bf16)src[e] : (__bf16)0.0f;
    } else {
        #pragma unroll
        for (int e = 0; e < 8; e++) o[e] = (__bf16)0.0f;
    }
    *reinterpret_cast<bf16x8*>(out + ((long)t * outrows + r) * outcols + cc) = o;
}

__global__ __launch_bounds__(256) void front_k(
    const float* __restrict__ w1t, const float* __restrict__ w2t,
    const float* __restrict__ w1c, const float* __restrict__ w2c,
    __bf16* __restrict__ o1t, __bf16* __restrict__ o2t,
    __bf16* __restrict__ o1c, __bf16* __restrict__ o2c,
    const float* __restrict__ x, const int* __restrict__ tasks,
    const float* __restrict__ cln, __bf16* __restrict__ h1T)
{
    constexpr int RPB = 32, LDT = Dc + 8;
    __shared__ unsigned short T[RPB * LDT];        // 48.5 KB (ln1 part only)
    const int bid = blockIdx.x;
    if (bid < CVT_BLK) {
        const int c = bid * 256 + threadIdx.x;
        if (c < CB0)      cvt_one(w1t, o1t, ISc, ISp, Sc,  Sc,  c);
        else if (c < CB1) cvt_one(w2t, o2t, Sc,  Sc,  ISc, ISp, c - CB0);
        else if (c < CB2) cvt_one(w1c, o1c, IDc, IDp, Dc,  Dc,  c - CB1);
        else              cvt_one(w2c, o2c, Dc,  Dc,  IDc, IDp, c - CB2);
        return;
    }
    const int idx = bid - CVT_BLK;
    const int b   = idx >> 5;
    const int s0  = (idx & 31) * RPB;
    const int t   = tasks[b];
    const int tid = threadIdx.x;
    const int wv  = tid >> 6;
    const int l   = tid & 63;

    const float4* Ga = reinterpret_cast<const float4*>(cln + (long)t * 2 * Dc);
    const float4* Be = reinterpret_cast<const float4*>(cln + (long)t * 2 * Dc + Dc);
    const float4 g0 = Ga[l], g1 = Ga[l + 64], g2 = Ga[l + 128];
    const float4 b0 = Be[l], b1 = Be[l + 64], b2 = Be[l + 128];

    #pragma unroll
    for (int rr = 0; rr < 8; rr++) {
        const int r = wv * 8 + rr;
        const float4* xr = reinterpret_cast<const float4*>(x + ((long)b * Sc + s0 + r) * Dc);
        const float4 v0 = xr[l], v1 = xr[l + 64], v2 = xr[l + 128];
        float s = v0.x + v0.y + v0.z + v0.w + v1.x + v1.y + v1.z + v1.w
                + v2.x + v2.y + v2.z + v2.w;
        float q = v0.x*v0.x + v0.y*v0.y + v0.z*v0.z + v0.w*v0.w
                + v1.x*v1.x + v1.y*v1.y + v1.z*v1.z + v1.w*v1.w
                + v2.x*v2.x + v2.y*v2.y + v2.z*v2.z + v2.w*v2.w;
        #pragma unroll
        for (int o = 1; o < 64; o <<= 1) { s += __shfl_xor(s, o); q += __shfl_xor(q, o); }
        const float mu   = s * (1.0f / Dc);
        const float var  = fmaxf(q * (1.0f / Dc) - mu * mu, 0.0f);
        const float rstd = 1.0f / sqrtf(var + 1e-5f);
        unsigned short* tr = &T[r * LDT];
        bf16x4 o0, o1, o2;
        o0[0] = (__bf16)(g0.x * ((v0.x - mu) * rstd) + b0.x);
        o0[1] = (__bf16)(g0.y * ((v0.y - mu) * rstd) + b0.y);
        o0[2] = (__bf16)(g0.z * ((v0.z - mu) * rstd) + b0.z);
        o0[3] = (__bf16)(g0.w * ((v0.w - mu) * rstd) + b0.w);
        o1[0] = (__bf16)(g1.x * ((v1.x - mu) * rstd) + b1.x);
        o1[1] = (__bf16)(g1.y * ((v1.y - mu) * rstd) + b1.y);
        o1[2] = (__bf16)(g1.z * ((v1.z - mu) * rstd) + b1.z);
        o1[3] = (__bf16)(g1.w * ((v1.w - mu) * rstd) + b1.w);
        o2[0] = (__bf16)(g2.x * ((v2.x - mu) * rstd) + b2.x);
        o2[1] = (__bf16)(g2.y * ((v2.y - mu) * rstd) + b2.y);
        o2[2] = (__bf16)(g2.z * ((v2.z - mu) * rstd) + b2.z);
        o2[3] = (__bf16)(g2.w * ((v2.w - mu) * rstd) + b2.w);
        *reinterpret_cast<bf16x4*>(&tr[l * 4])        = o0;
        *reinterpret_cast<bf16x4*>(&tr[256 + l * 4])  = o1;
        *reinterpret_cast<bf16x4*>(&tr[512 + l * 4])  = o2;
    }
    __syncthreads();
    #pragma unroll
    for (int c = 0; c < 3; c++) {
        const int d = tid + c * 256;
        unsigned short tmp[32];
        #pragma unroll
        for (int e = 0; e < 32; e++) tmp[e] = T[e * LDT + d];
        __bf16* dst = h1T + ((long)b * Dc + d) * Sc + s0;
        #pragma unroll
        for (int u = 0; u < 4; u++)
            reinterpret_cast<uint4*>(dst)[u] = reinterpret_cast<const uint4*>(tmp)[u];
    }
}

// ---------------- bf16 TN MFMA GEMM: 512 threads, 8 waves (4m x 2n) --------
// RESM residual reads hoisted pre-K-loop (T14): res[2][4][4]=+32 VGPR (64->96
// < 128 cap @4 waves/EU); occupancy is LDS-bound (64KB -> 2 blocks/CU) so
// unchanged — unlike R6 where the VGPR cap was binding.
template<int DOGELU, int RESM, int OUTF32, int ATASK>
__global__ __launch_bounds__(512, 4) void gemm_tn(
    const __bf16* __restrict__ A, long sA, int lda,
    const __bf16* __restrict__ B, long sB, int ldb,
    const void* __restrict__ R, long sR,
    void* __restrict__ C, long sC, int ldc,
    const int* __restrict__ tasks, int M, int N, int K)
{
    constexpr int BM = 128, BN = 128, BK = 64;
    constexpr int BUFB = 32768;
    __shared__ uint4 lds4[2 * BUFB / 16];       // 64 KB
    char* lbase = (char*)lds4;

    const int gx  = gridDim.x, gy = gridDim.y;
    const int tpb = gx * gy;
    const long lin = blockIdx.x + (long)gx * (blockIdx.y + (long)gy * blockIdx.z);
    const int  xcd  = (int)(lin & 7);
    const long idx  = lin >> 3;
    const int  lb   = (int)(idx / tpb);
    const int  tile = (int)(idx - (long)lb * tpb);
    const int  b    = xcd * 8 + lb;
    const int  m0   = (tile / gx) * BM;
    const int  n0   = (tile % gx) * BN;

    const int t = tasks[b];
    const __bf16* Ab = A + (ATASK ? (long)t : (long)b) * sA;
    const __bf16* Bb = B + (ATASK ? (long)b : (long)t) * sB;
    const int tid = threadIdx.x, lane = tid & 63, wid = tid >> 6;
    const int wm = (wid >> 1) * 32, wn = (wid & 1) * 64;   // 4m x 2n
    const int l15 = lane & 15, l4 = lane >> 4;

    const float*  Rf = (RESM == 1) ? ((const float*)R  + (long)b * sR) : nullptr;
    const __bf16* Rh = (RESM == 2) ? ((const __bf16*)R + (long)b * sR) : nullptr;

    // T14: issue residual loads before the K-loop; consumed in the epilogue.
    float res[2][4][4];
    if constexpr (RESM != 0) {
        #pragma unroll
        for (int i = 0; i < 2; i++)
            #pragma unroll
            for (int j = 0; j < 4; j++) {
                const int gn = n0 + wn + j * 16 + l15;
                #pragma unroll
                for (int r = 0; r < 4; r++) {
                    const int gm = m0 + wm + i * 16 + l4 * 4 + r;
                    float rv = 0.0f;
                    if (gm < M && gn < N) {
                        if (RESM == 1) rv = Rf[(long)gm * ldc + gn];
                        else           rv = (float)Rh[(long)gm * ldc + gn];
                    }
                    res[i][j][r] = rv;
                }
            }
    }

    f32x4 acc[2][4];
    #pragma unroll
    for (int i = 0; i < 2; i++)
        #pragma unroll
        for (int j = 0; j < 4; j++)
            acc[i][j] = (f32x4){0.f, 0.f, 0.f, 0.f};

    auto STAGE = [&](int k0, int buf) {
        char* dst = lbase + buf * BUFB;
        #pragma unroll
        for (int rep = 0; rep < 2; rep++) {
            const int c = rep * 512 + tid;
            const int m = c >> 3, ch = c & 7;
            const int gk = k0 + ((ch ^ (m & 7)) << 3);
            gload16(Ab + (long)(m0 + m) * lda + gk, dst + c * 16);
        }
        #pragma unroll
        for (int rep = 0; rep < 2; rep++) {
            const int c = rep * 512 + tid;
            const int n = c >> 3, ch = c & 7;
            const int gk = k0 + ((ch ^ (n & 7)) << 3);
            gload16(Bb + (long)(n0 + n) * ldb + gk, dst + 16384 + c * 16);
        }
    };

    const int nt = K / BK;
    STAGE(0, 0);
    __syncthreads();
    int cur = 0;
    for (int tt = 0; tt < nt; tt++) {
        if (tt + 1 < nt) STAGE((tt + 1) * BK, cur ^ 1);
        const char* bb = lbase + cur * BUFB;
        #pragma unroll
        for (int h = 0; h < 2; h++) {
            bf16x8 af[2], bfr[4];
            #pragma unroll
            for (int i = 0; i < 2; i++) {
                const int row = wm + i * 16 + l15;
                af[i] = *reinterpret_cast<const bf16x8*>(
                    bb + row * 128 + (((h * 4 + l4) ^ (row & 7)) << 4));
            }
            #pragma unroll
            for (int j = 0; j < 4; j++) {
                const int row = wn + j * 16 + l15;
                bfr[j] = *reinterpret_cast<const bf16x8*>(
                    bb + 16384 + row * 128 + (((h * 4 + l4) ^ (row & 7)) << 4));
            }
            #pragma unroll
            for (int i = 0; i < 2; i++)
                #pragma unroll
                for (int j = 0; j < 4; j++)
                    acc[i][j] = __builtin_amdgcn_mfma_f32_16x16x32_bf16(af[i], bfr[j], acc[i][j], 0, 0, 0);
        }
        __syncthreads();
        cur ^= 1;
    }

    float*  Cf = (float*)C  + (long)b * sC;
    __bf16* Ch = (__bf16*)C + (long)b * sC;

    #pragma unroll
    for (int i = 0; i < 2; i++) {
        #pragma unroll
        for (int j = 0; j < 4; j++) {
            const int gn = n0 + wn + j * 16 + l15;
            if (gn >= N) continue;
            #pragma unroll
            for (int r = 0; r < 4; r++) {
                const int gm = m0 + wm + i * 16 + l4 * 4 + r;
                if (gm >= M) continue;
                float v = acc[i][j][r];
                if (DOGELU) v = gelu_f(v);
                if (RESM != 0) v += res[i][j][r];
                if (OUTF32) Cf[(long)gm * ldc + gn] = v;
                else        Ch[(long)gm * ldc + gn] = (__bf16)v;
            }
        }
    }
}

// ---------------- fused channel-MLP: out = x1 + gelu(LN2(x1)@W1ch^T)@W2ch^T
// R17-proven version: 64-row tile, 512 threads = 8 waves (2m x 4n),
// 2 blocks/CU (72.5 KB LDS). LDS-staged A (coalesced, LN in xformA),
// involution f(x)=(x>>1)&3 both sides, fast GELU, T14 residual prefetch.
__global__ __launch_bounds__(512, 4) void mlp_ch(
    const __bf16* __restrict__ x1, const int* __restrict__ tasks,
    const float* __restrict__ cln2,
    const __bf16* __restrict__ wC1,   // [10][IDp][Dc] k-contig
    const __bf16* __restrict__ wC2,   // [10][Dc][IDp] k-contig
    float* __restrict__ out)
{
    __shared__ float2 st[64];
    __shared__ unsigned short G[64 * 256];     // 32 KB
    __shared__ char sbuf[2][20480];            // 40 KB

    const int lin = blockIdx.x;
    const int xcd = lin & 7;
    const int idx = lin >> 3;                  // 0..127
    const int b   = xcd * 8 + (idx >> 4);
    const int m0  = (idx & 15) * 64;
    const int t   = tasks[b];

    const int tid = threadIdx.x;
    const int wid = tid >> 6, lane = tid & 63;
    const int wm  = (wid >> 2) * 32, wn = (wid & 3) * 64;   // 2m x 4n
    const int l15 = lane & 15, l4 = lane >> 4;

    const __bf16* xb = x1 + ((long)b * Sc + m0) * Dc;
    const float*  cg = cln2 + (long)t * 2 * Dc;
    const float*  cb = cg + Dc;

    // ---- LN2 stats: wave w -> rows w*8..w*8+7 ----
    #pragma unroll 2
    for (int rr = 0; rr < 8; rr++) {
        const int m = wid * 8 + rr;
        const ushort4* xr = reinterpret_cast<const ushort4*>(xb + (long)m * Dc);
        const ushort4 u0 = xr[lane], u1 = xr[lane + 64], u2 = xr[lane + 128];
        float s = 0.f, q = 0.f, v;
        v = bf2f(u0.x); s += v; q += v*v;  v = bf2f(u0.y); s += v; q += v*v;
        v = bf2f(u0.z); s += v; q += v*v;  v = bf2f(u0.w); s += v; q += v*v;
        v = bf2f(u1.x); s += v; q += v*v;  v = bf2f(u1.y); s += v; q += v*v;
        v = bf2f(u1.z); s += v; q += v*v;  v = bf2f(u1.w); s += v; q += v*v;
        v = bf2f(u2.x); s += v; q += v*v;  v = bf2f(u2.y); s += v; q += v*v;
        v = bf2f(u2.z); s += v; q += v*v;  v = bf2f(u2.w); s += v; q += v*v;
        #pragma unroll
        for (int o = 1; o < 64; o <<= 1) { s += __shfl_xor(s, o); q += __shfl_xor(q, o); }
        if (lane == 0) {
            const float mu  = s * (1.0f / Dc);
            const float var = fmaxf(q * (1.0f / Dc) - mu * mu, 0.0f);
            st[m] = make_float2(mu, 1.0f / sqrtf(var + 1e-5f));
        }
    }
    __syncthreads();

    // ---- stage 1: Gtile(64x256) = gelu(LN2(x1) @ wC1^T), K=768, BK=32 ----
    const int am = tid >> 3, ach8 = tid & 7;
    const float2 ams = st[am];
    const __bf16* arow = xb + (long)am * Dc;

    auto loadA = [&](int kt) -> bf16x4 {
        return *reinterpret_cast<const bf16x4*>(arow + kt * 32 + ach8 * 4);
    };
    auto writeA = [&](bf16x4 a, int buf) {
        const int phys = (ach8 >> 1) ^ ((am >> 1) & 3);
        *reinterpret_cast<bf16x4*>(
            sbuf[buf] + am * 64 + (phys << 4) + (ach8 & 1) * 8) = a;
    };
    auto stageB1 = [&](int kt, int buf) {
        #pragma unroll
        for (int rep = 0; rep < 2; rep++) {
            const int c = rep * 512 + tid;
            const int n = c >> 2, ch = c & 3;
            const int gk = kt * 32 + ((ch ^ ((n >> 1) & 3)) << 3);
            gload16(wC1 + ((long)t * IDp + n) * Dc + gk, sbuf[buf] + 4096 + c * 16);
        }
    };
    auto xformA = [&](bf16x4 raw, int kt) -> bf16x4 {
        const int gk = kt * 32 + ach8 * 4;
        const float4 ga = *reinterpret_cast<const float4*>(cg + gk);
        const float4 be = *reinterpret_cast<const float4*>(cb + gk);
        bf16x4 o;
        o[0] = (__bf16)(ga.x * ((float)raw[0] - ams.x) * ams.y + be.x);
        o[1] = (__bf16)(ga.y * ((float)raw[1] - ams.x) * ams.y + be.y);
        o[2] = (__bf16)(ga.z * ((float)raw[2] - ams.x) * ams.y + be.z);
        o[3] = (__bf16)(ga.w * ((float)raw[3] - ams.x) * ams.y + be.w);
        return o;
    };
    const __bf16* w2b = wC2 + (long)t * Dc * IDp;
    auto stageB2 = [&](int nc, int kt, int buf) {
        #pragma unroll
        for (int rep = 0; rep < 2; rep++) {
            const int c = rep * 512 + tid;
            const int n = c >> 2, ch = c & 3;
            const int gk = kt * 32 + ((ch ^ ((n >> 1) & 3)) << 3);
            gload16(w2b + (long)(nc * 256 + n) * IDp + gk, sbuf[buf] + c * 16);
        }
    };

    f32x4 acc[2][4];
    #pragma unroll
    for (int i = 0; i < 2; i++)
        #pragma unroll
        for (int j = 0; j < 4; j++)
            acc[i][j] = (f32x4){0.f, 0.f, 0.f, 0.f};

    {
        bf16x4 a0 = loadA(0);
        stageB1(0, 0);
        writeA(xformA(a0, 0), 0);
        __syncthreads();
        for (int kt = 0; kt < 24; kt++) {
            const int buf = kt & 1;
            bf16x4 anx;
            if (kt < 23) { anx = loadA(kt + 1); stageB1(kt + 1, buf ^ 1); }
            const char* Abase = sbuf[buf];
            const char* Bbase = sbuf[buf] + 4096;
            bf16x8 af[2], bfr[4];
            #pragma unroll
            for (int i = 0; i < 2; i++) {
                const int row = wm + i * 16 + l15;
                af[i] = *reinterpret_cast<const bf16x8*>(
                    Abase + row * 64 + ((l4 ^ ((row >> 1) & 3)) << 4));
            }
            #pragma unroll
            for (int j = 0; j < 4; j++) {
                const int row = wn + j * 16 + l15;
                bfr[j] = *reinterpret_cast<const bf16x8*>(
                    Bbase + row * 64 + ((l4 ^ ((row >> 1) & 3)) << 4));
            }
            #pragma unroll
            for (int i = 0; i < 2; i++)
                #pragma unroll
                for (int j = 0; j < 4; j++)
                    acc[i][j] = __builtin_amdgcn_mfma_f32_16x16x32_bf16(af[i], bfr[j], acc[i][j], 0, 0, 0);
            if (kt < 23) writeA(xformA(anx, kt + 1), buf ^ 1);
            __syncthreads();
        }
    }

    // prefetch first stage-2 B tile (overlaps the G-write epilogue)
    stageB2(0, 0, 0);

    // stage-1 epilogue: gelu -> G ([m][k] swizzled, phys = chunk ^ (m&7))
    #pragma unroll
    for (int i = 0; i < 2; i++) {
        #pragma unroll
        for (int j = 0; j < 4; j++) {
            const int k = wn + j * 16 + l15;
            #pragma unroll
            for (int r = 0; r < 4; r++) {
                const int m = wm + i * 16 + l4 * 4 + r;
                const float v = gelu_f(acc[i][j][r]);
                const int phys = (k >> 3) ^ (m & 7);
                G[m * 256 + phys * 8 + (k & 7)] =
                    __builtin_bit_cast(unsigned short, (__bf16)v);
            }
        }
    }
    __syncthreads();

    // ---- stage 2: out = x1 + G @ wC2^T, 3 n-passes of 256, K=256, BK=32 ----
    float* ob = out + ((long)b * Sc + m0) * Dc;
    for (int nc = 0; nc < 3; nc++) {
        f32x4 a2[2][4];
        #pragma unroll
        for (int i = 0; i < 2; i++)
            #pragma unroll
            for (int j = 0; j < 4; j++)
                a2[i][j] = (f32x4){0.f, 0.f, 0.f, 0.f};

        // T14: residual loads issued now, consumed in the epilogue
        float res[2][4][4];
        #pragma unroll
        for (int i = 0; i < 2; i++)
            #pragma unroll
            for (int j = 0; j < 4; j++) {
                const int gn = nc * 256 + wn + j * 16 + l15;
                #pragma unroll
                for (int r = 0; r < 4; r++) {
                    const int gm = wm + i * 16 + l4 * 4 + r;
                    res[i][j][r] = (float)xb[(long)gm * Dc + gn];
                }
            }

        for (int kt = 0; kt < 8; kt++) {
            const int buf = kt & 1;
            if (kt < 7)       stageB2(nc, kt + 1, buf ^ 1);
            else if (nc < 2)  stageB2(nc + 1, 0, buf ^ 1);
            bf16x8 af[2], bfr[4];
            #pragma unroll
            for (int i = 0; i < 2; i++) {
                const int row = wm + i * 16 + l15;
                const int phys = (kt * 4 + l4) ^ (row & 7);
                af[i] = *reinterpret_cast<const bf16x8*>(
                    (const char*)G + row * 512 + phys * 16);
            }
            #pragma unroll
            for (int j = 0; j < 4; j++) {
                const int row = wn + j * 16 + l15;
                bfr[j] = *reinterpret_cast<const bf16x8*>(
                    sbuf[buf] + row * 64 + ((l4 ^ ((row >> 1) & 3)) << 4));
            }
            #pragma unroll
            for (int i = 0; i < 2; i++)
                #pragma unroll
                for (int j = 0; j < 4; j++)
                    a2[i][j] = __builtin_amdgcn_mfma_f32_16x16x32_bf16(af[i], bfr[j], a2[i][j], 0, 0, 0);
            __syncthreads();
        }
        #pragma unroll
        for (int i = 0; i < 2; i++) {
            #pragma unroll
            for (int j = 0; j < 4; j++) {
                const int gn = nc * 256 + wn + j * 16 + l15;
                #pragma unroll
                for (int r = 0; r < 4; r++) {
                    const int gm = wm + i * 16 + l4 * 4 + r;
                    ob[(long)gm * Dc + gn] = a2[i][j][r] + res[i][j][r];
                }
            }
        }
    }
}

extern "C" void kernel_launch(void* const* d_in, const int* in_sizes, int n_in,
                              void* d_out, int out_size, void* d_ws, size_t ws_size,
                              hipStream_t stream) {
    const float* x      = (const float*)d_in[0];
    const int*   tasks  = (const int*)  d_in[1];
    const float* cln1   = (const float*)d_in[2];
    const float* cln2   = (const float*)d_in[3];
    const float* w1_tok = (const float*)d_in[4];
    const float* w2_tok = (const float*)d_in[5];
    const float* w1_ch  = (const float*)d_in[6];
    const float* w2_ch  = (const float*)d_in[7];
    float* out = (float*)d_out;

    char* ws = (char*)d_ws;
    const long oT1 = 0;
    const long oT2 = oT1 + (long)10 * ISp * Sc * 2;
    const long oC1 = oT2 + (long)10 * Sc * ISp * 2;
    const long oC2 = oC1 + (long)10 * IDp * Dc * 2;
    const long oA  = oC2 + (long)10 * Dc * IDp * 2;
    const long oG  = oA  + (long)Bc * Dc * Sc * 2;
    __bf16* wT1  = (__bf16*)(ws + oT1);
    __bf16* wT2  = (__bf16*)(ws + oT2);
    __bf16* wC1  = (__bf16*)(ws + oC1);
    __bf16* wC2  = (__bf16*)(ws + oC2);
    __bf16* h1T  = (__bf16*)(ws + oA);
    __bf16* x1   = (__bf16*)(ws + oA);     // reuses h1T (dead after GEMM2)
    __bf16* gbf  = (__bf16*)(ws + oG);

    // 0+1) fused: weight conversions + LN1-transpose (independent work)
    front_k<<<CVT_BLK + LN1_BLK, 256, 0, stream>>>(
        w1_tok, w2_tok, w1_ch, w2_ch, wT1, wT2, wC1, wC2,
        x, tasks, cln1, h1T);

    // GT = gelu(h1T @ W1tok[t]^T)   M=768, N=384, K=1024
    gemm_tn<1, 0, 0, 0><<<dim3(ISp / 128, Dc / 128, Bc), 512, 0, stream>>>(
        h1T, (long)Dc * Sc, Sc,
        wT1, (long)ISp * Sc, Sc,
        nullptr, 0,
        gbf, (long)Dc * ISp, ISp,
        tasks, Dc, ISp, Sc);

    // x1 = x + W2tok[t] @ GT^T   M=1024, N=768, K=384
    gemm_tn<0, 1, 0, 1><<<dim3(Dc / 128, Sc / 128, Bc), 512, 0, stream>>>(
        wT2, (long)Sc * ISp, ISp,
        gbf, (long)Dc * ISp, ISp,
        x, (long)Sc * Dc,
        x1, (long)Sc * Dc, Dc,
        tasks, Sc, Dc, ISp);

    // out = x1 + gelu(LN2(x1) @ W1ch^T) @ W2ch^T   (fused, 64-row x 512-thread)
    mlp_ch<<<(Sc / 64) * Bc, 512, 0, stream>>>(x1, tasks, cln2, wC1, wC2, out);
}

// Round 22
// 404.241 us; speedup vs baseline: 1.0187x; 1.0187x over previous
//
#include <hip/hip_runtime.h>
#include <math.h>

typedef __bf16 bf16x8 __attribute__((ext_vector_type(8)));
typedef __bf16 bf16x4 __attribute__((ext_vector_type(4)));
typedef float  f32x4  __attribute__((ext_vector_type(4)));

constexpr int Bc = 64, Sc = 1024, Dc = 768;
constexpr int ISc = 307, IDc = 230;
constexpr int ISp = 384, IDp = 256;   // padded: every GEMM M,N %128==0, K %64==0

static __device__ __forceinline__ float bf2f(unsigned short u) {
    return __builtin_bit_cast(float, (unsigned)u << 16);
}
// tanh-form GELU via exp2/rcp (trans pipe); |delta| vs erf-gelu ~3e-3 (safe).
static __device__ __forceinline__ float gelu_f(float v) {
    const float y = v * (0.7978845608f + 0.0356774081f * v * v);
    const float e = __builtin_amdgcn_exp2f(y * 2.8853900818f);
    return v * e * __builtin_amdgcn_rcpf(e + 1.0f);
}

// async global->LDS, 16B/lane, linear LDS dest (wave-uniform base + lane*16)
static __device__ __forceinline__ void gload16(const void* g, void* l) {
    __builtin_amdgcn_global_load_lds(
        (const __attribute__((address_space(1))) void*)g,
        (__attribute__((address_space(3))) void*)l, 16, 0, 0);
}

// ---------------- fused front kernel: weight cvt + LN1-transpose ----------
constexpr int CH0 = 10 * ISp * (Sc  / 8);
constexpr int CH1 = 10 * Sc  * (ISp / 8);
constexpr int CH2 = 10 * IDp * (Dc  / 8);
constexpr int CH3 = 10 * Dc  * (IDp / 8);
constexpr int CB0 = CH0, CB1 = CB0 + CH1, CB2 = CB1 + CH2, CB3 = CB2 + CH3;
constexpr int CVT_BLK = CB3 / 256;          // 5760 exactly
constexpr int LN1_BLK = (Sc / 32) * Bc;     // 2048

__device__ __forceinline__ void cvt_one(
    const float* __restrict__ in, __bf16* __restrict__ out,
    int inrows, int outrows, int incols, int outcols, int c)
{
    const int cpr  = outcols >> 3;
    const int perT = outrows * cpr;
    const int t    = c / perT;
    const int rem  = c - t * perT;
    const int r    = rem / cpr;
    const int cc   = (rem - r * cpr) * 8;
    bf16x8 o;
    if (r < inrows) {
        const float* src = in + ((long)t * inrows + r) * incols + cc;
        #pragma unroll
        for (int e = 0; e < 8; e++)
            o[e] = (cc + e < incols) ? (__bf16)src[e] : (__bf16)0.0f;
    } else {
        #pragma unroll
        for (int e = 0; e < 8; e++) o[e] = (__bf16)0.0f;
    }
    *reinterpret_cast<bf16x8*>(out + ((long)t * outrows + r) * outcols + cc) = o;
}

__global__ __launch_bounds__(256) void front_k(
    const float* __restrict__ w1t, const float* __restrict__ w2t,
    const float* __restrict__ w1c, const float* __restrict__ w2c,
    __bf16* __restrict__ o1t, __bf16* __restrict__ o2t,
    __bf16* __restrict__ o1c, __bf16* __restrict__ o2c,
    const float* __restrict__ x, const int* __restrict__ tasks,
    const float* __restrict__ cln, __bf16* __restrict__ h1T)
{
    constexpr int RPB = 32, LDT = Dc + 8;
    __shared__ unsigned short T[RPB * LDT];        // 48.5 KB (ln1 part only)
    const int bid = blockIdx.x;
    if (bid < CVT_BLK) {
        const int c = bid * 256 + threadIdx.x;
        if (c < CB0)      cvt_one(w1t, o1t, ISc, ISp, Sc,  Sc,  c);
        else if (c < CB1) cvt_one(w2t, o2t, Sc,  Sc,  ISc, ISp, c - CB0);
        else if (c < CB2) cvt_one(w1c, o1c, IDc, IDp, Dc,  Dc,  c - CB1);
        else              cvt_one(w2c, o2c, Dc,  Dc,  IDc, IDp, c - CB2);
        return;
    }
    const int idx = bid - CVT_BLK;
    const int b   = idx >> 5;
    const int s0  = (idx & 31) * RPB;
    const int t   = tasks[b];
    const int tid = threadIdx.x;
    const int wv  = tid >> 6;
    const int l   = tid & 63;

    const float4* Ga = reinterpret_cast<const float4*>(cln + (long)t * 2 * Dc);
    const float4* Be = reinterpret_cast<const float4*>(cln + (long)t * 2 * Dc + Dc);
    const float4 g0 = Ga[l], g1 = Ga[l + 64], g2 = Ga[l + 128];
    const float4 b0 = Be[l], b1 = Be[l + 64], b2 = Be[l + 128];

    #pragma unroll
    for (int rr = 0; rr < 8; rr++) {
        const int r = wv * 8 + rr;
        const float4* xr = reinterpret_cast<const float4*>(x + ((long)b * Sc + s0 + r) * Dc);
        const float4 v0 = xr[l], v1 = xr[l + 64], v2 = xr[l + 128];
        float s = v0.x + v0.y + v0.z + v0.w + v1.x + v1.y + v1.z + v1.w
                + v2.x + v2.y + v2.z + v2.w;
        float q = v0.x*v0.x + v0.y*v0.y + v0.z*v0.z + v0.w*v0.w
                + v1.x*v1.x + v1.y*v1.y + v1.z*v1.z + v1.w*v1.w
                + v2.x*v2.x + v2.y*v2.y + v2.z*v2.z + v2.w*v2.w;
        #pragma unroll
        for (int o = 1; o < 64; o <<= 1) { s += __shfl_xor(s, o); q += __shfl_xor(q, o); }
        const float mu   = s * (1.0f / Dc);
        const float var  = fmaxf(q * (1.0f / Dc) - mu * mu, 0.0f);
        const float rstd = 1.0f / sqrtf(var + 1e-5f);
        unsigned short* tr = &T[r * LDT];
        bf16x4 o0, o1, o2;
        o0[0] = (__bf16)(g0.x * ((v0.x - mu) * rstd) + b0.x);
        o0[1] = (__bf16)(g0.y * ((v0.y - mu) * rstd) + b0.y);
        o0[2] = (__bf16)(g0.z * ((v0.z - mu) * rstd) + b0.z);
        o0[3] = (__bf16)(g0.w * ((v0.w - mu) * rstd) + b0.w);
        o1[0] = (__bf16)(g1.x * ((v1.x - mu) * rstd) + b1.x);
        o1[1] = (__bf16)(g1.y * ((v1.y - mu) * rstd) + b1.y);
        o1[2] = (__bf16)(g1.z * ((v1.z - mu) * rstd) + b1.z);
        o1[3] = (__bf16)(g1.w * ((v1.w - mu) * rstd) + b1.w);
        o2[0] = (__bf16)(g2.x * ((v2.x - mu) * rstd) + b2.x);
        o2[1] = (__bf16)(g2.y * ((v2.y - mu) * rstd) + b2.y);
        o2[2] = (__bf16)(g2.z * ((v2.z - mu) * rstd) + b2.z);
        o2[3] = (__bf16)(g2.w * ((v2.w - mu) * rstd) + b2.w);
        *reinterpret_cast<bf16x4*>(&tr[l * 4])        = o0;
        *reinterpret_cast<bf16x4*>(&tr[256 + l * 4])  = o1;
        *reinterpret_cast<bf16x4*>(&tr[512 + l * 4])  = o2;
    }
    __syncthreads();
    #pragma unroll
    for (int c = 0; c < 3; c++) {
        const int d = tid + c * 256;
        unsigned short tmp[32];
        #pragma unroll
        for (int e = 0; e < 32; e++) tmp[e] = T[e * LDT + d];
        __bf16* dst = h1T + ((long)b * Dc + d) * Sc + s0;
        #pragma unroll
        for (int u = 0; u < 4; u++)
            reinterpret_cast<uint4*>(dst)[u] = reinterpret_cast<const uint4*>(tmp)[u];
    }
}

// ---------------- bf16 TN MFMA GEMM: 512 threads, 8 waves (4m x 2n) --------
// R20-proven: epilogue residual (T14 prefetch here measured neutral, R21).
template<int DOGELU, int RESM, int OUTF32, int ATASK>
__global__ __launch_bounds__(512, 4) void gemm_tn(
    const __bf16* __restrict__ A, long sA, int lda,
    const __bf16* __restrict__ B, long sB, int ldb,
    const void* __restrict__ R, long sR,
    void* __restrict__ C, long sC, int ldc,
    const int* __restrict__ tasks, int M, int N, int K)
{
    constexpr int BM = 128, BN = 128, BK = 64;
    constexpr int BUFB = 32768;
    __shared__ uint4 lds4[2 * BUFB / 16];       // 64 KB
    char* lbase = (char*)lds4;

    const int gx  = gridDim.x, gy = gridDim.y;
    const int tpb = gx * gy;
    const long lin = blockIdx.x + (long)gx * (blockIdx.y + (long)gy * blockIdx.z);
    const int  xcd  = (int)(lin & 7);
    const long idx  = lin >> 3;
    const int  lb   = (int)(idx / tpb);
    const int  tile = (int)(idx - (long)lb * tpb);
    const int  b    = xcd * 8 + lb;
    const int  m0   = (tile / gx) * BM;
    const int  n0   = (tile % gx) * BN;

    const int t = tasks[b];
    const __bf16* Ab = A + (ATASK ? (long)t : (long)b) * sA;
    const __bf16* Bb = B + (ATASK ? (long)b : (long)t) * sB;
    const int tid = threadIdx.x, lane = tid & 63, wid = tid >> 6;
    const int wm = (wid >> 1) * 32, wn = (wid & 1) * 64;   // 4m x 2n
    const int l15 = lane & 15, l4 = lane >> 4;

    f32x4 acc[2][4];
    #pragma unroll
    for (int i = 0; i < 2; i++)
        #pragma unroll
        for (int j = 0; j < 4; j++)
            acc[i][j] = (f32x4){0.f, 0.f, 0.f, 0.f};

    auto STAGE = [&](int k0, int buf) {
        char* dst = lbase + buf * BUFB;
        #pragma unroll
        for (int rep = 0; rep < 2; rep++) {
            const int c = rep * 512 + tid;
            const int m = c >> 3, ch = c & 7;
            const int gk = k0 + ((ch ^ (m & 7)) << 3);
            gload16(Ab + (long)(m0 + m) * lda + gk, dst + c * 16);
        }
        #pragma unroll
        for (int rep = 0; rep < 2; rep++) {
            const int c = rep * 512 + tid;
            const int n = c >> 3, ch = c & 7;
            const int gk = k0 + ((ch ^ (n & 7)) << 3);
            gload16(Bb + (long)(n0 + n) * ldb + gk, dst + 16384 + c * 16);
        }
    };

    const int nt = K / BK;
    STAGE(0, 0);
    __syncthreads();
    int cur = 0;
    for (int tt = 0; tt < nt; tt++) {
        if (tt + 1 < nt) STAGE((tt + 1) * BK, cur ^ 1);
        const char* bb = lbase + cur * BUFB;
        #pragma unroll
        for (int h = 0; h < 2; h++) {
            bf16x8 af[2], bfr[4];
            #pragma unroll
            for (int i = 0; i < 2; i++) {
                const int row = wm + i * 16 + l15;
                af[i] = *reinterpret_cast<const bf16x8*>(
                    bb + row * 128 + (((h * 4 + l4) ^ (row & 7)) << 4));
            }
            #pragma unroll
            for (int j = 0; j < 4; j++) {
                const int row = wn + j * 16 + l15;
                bfr[j] = *reinterpret_cast<const bf16x8*>(
                    bb + 16384 + row * 128 + (((h * 4 + l4) ^ (row & 7)) << 4));
            }
            #pragma unroll
            for (int i = 0; i < 2; i++)
                #pragma unroll
                for (int j = 0; j < 4; j++)
                    acc[i][j] = __builtin_amdgcn_mfma_f32_16x16x32_bf16(af[i], bfr[j], acc[i][j], 0, 0, 0);
        }
        __syncthreads();
        cur ^= 1;
    }

    float*  Cf = (float*)C  + (long)b * sC;
    __bf16* Ch = (__bf16*)C + (long)b * sC;
    const float*  Rf = (RESM == 1) ? ((const float*)R  + (long)b * sR) : nullptr;
    const __bf16* Rh = (RESM == 2) ? ((const __bf16*)R + (long)b * sR) : nullptr;

    #pragma unroll
    for (int i = 0; i < 2; i++) {
        #pragma unroll
        for (int j = 0; j < 4; j++) {
            const int gn = n0 + wn + j * 16 + l15;
            #pragma unroll
            for (int r = 0; r < 4; r++) {
                const int gm = m0 + wm + i * 16 + l4 * 4 + r;
                float v = acc[i][j][r];
                if (DOGELU) v = gelu_f(v);
                if (RESM == 1) v += Rf[(long)gm * ldc + gn];
                if (RESM == 2) v += (float)Rh[(long)gm * ldc + gn];
                if (OUTF32) Cf[(long)gm * ldc + gn] = v;
                else        Ch[(long)gm * ldc + gn] = (__bf16)v;
            }
        }
    }
}

// ---------------- fused channel-MLP: out = x1 + gelu(LN2(x1)@W1ch^T)@W2ch^T
// R17/R20-proven: 64-row tile, 512 threads = 8 waves (2m x 4n),
// 2 blocks/CU (72.5 KB LDS). LDS-staged A (coalesced, LN in xformA),
// involution f(x)=(x>>1)&3 both sides, fast GELU, T14 residual prefetch.
__global__ __launch_bounds__(512, 4) void mlp_ch(
    const __bf16* __restrict__ x1, const int* __restrict__ tasks,
    const float* __restrict__ cln2,
    const __bf16* __restrict__ wC1,   // [10][IDp][Dc] k-contig
    const __bf16* __restrict__ wC2,   // [10][Dc][IDp] k-contig
    float* __restrict__ out)
{
    __shared__ float2 st[64];
    __shared__ unsigned short G[64 * 256];     // 32 KB
    __shared__ char sbuf[2][20480];            // 40 KB

    const int lin = blockIdx.x;
    const int xcd = lin & 7;
    const int idx = lin >> 3;                  // 0..127
    const int b   = xcd * 8 + (idx >> 4);
    const int m0  = (idx & 15) * 64;
    const int t   = tasks[b];

    const int tid = threadIdx.x;
    const int wid = tid >> 6, lane = tid & 63;
    const int wm  = (wid >> 2) * 32, wn = (wid & 3) * 64;   // 2m x 4n
    const int l15 = lane & 15, l4 = lane >> 4;

    const __bf16* xb = x1 + ((long)b * Sc + m0) * Dc;
    const float*  cg = cln2 + (long)t * 2 * Dc;
    const float*  cb = cg + Dc;

    // ---- LN2 stats: wave w -> rows w*8..w*8+7 ----
    #pragma unroll 2
    for (int rr = 0; rr < 8; rr++) {
        const int m = wid * 8 + rr;
        const ushort4* xr = reinterpret_cast<const ushort4*>(xb + (long)m * Dc);
        const ushort4 u0 = xr[lane], u1 = xr[lane + 64], u2 = xr[lane + 128];
        float s = 0.f, q = 0.f, v;
        v = bf2f(u0.x); s += v; q += v*v;  v = bf2f(u0.y); s += v; q += v*v;
        v = bf2f(u0.z); s += v; q += v*v;  v = bf2f(u0.w); s += v; q += v*v;
        v = bf2f(u1.x); s += v; q += v*v;  v = bf2f(u1.y); s += v; q += v*v;
        v = bf2f(u1.z); s += v; q += v*v;  v = bf2f(u1.w); s += v; q += v*v;
        v = bf2f(u2.x); s += v; q += v*v;  v = bf2f(u2.y); s += v; q += v*v;
        v = bf2f(u2.z); s += v; q += v*v;  v = bf2f(u2.w); s += v; q += v*v;
        #pragma unroll
        for (int o = 1; o < 64; o <<= 1) { s += __shfl_xor(s, o); q += __shfl_xor(q, o); }
        if (lane == 0) {
            const float mu  = s * (1.0f / Dc);
            const float var = fmaxf(q * (1.0f / Dc) - mu * mu, 0.0f);
            st[m] = make_float2(mu, 1.0f / sqrtf(var + 1e-5f));
        }
    }
    __syncthreads();

    // ---- stage 1: Gtile(64x256) = gelu(LN2(x1) @ wC1^T), K=768, BK=32 ----
    const int am = tid >> 3, ach8 = tid & 7;
    const float2 ams = st[am];
    const __bf16* arow = xb + (long)am * Dc;

    auto loadA = [&](int kt) -> bf16x4 {
        return *reinterpret_cast<const bf16x4*>(arow + kt * 32 + ach8 * 4);
    };
    auto writeA = [&](bf16x4 a, int buf) {
        const int phys = (ach8 >> 1) ^ ((am >> 1) & 3);
        *reinterpret_cast<bf16x4*>(
            sbuf[buf] + am * 64 + (phys << 4) + (ach8 & 1) * 8) = a;
    };
    auto stageB1 = [&](int kt, int buf) {
        #pragma unroll
        for (int rep = 0; rep < 2; rep++) {
            const int c = rep * 512 + tid;
            const int n = c >> 2, ch = c & 3;
            const int gk = kt * 32 + ((ch ^ ((n >> 1) & 3)) << 3);
            gload16(wC1 + ((long)t * IDp + n) * Dc + gk, sbuf[buf] + 4096 + c * 16);
        }
    };
    auto xformA = [&](bf16x4 raw, int kt) -> bf16x4 {
        const int gk = kt * 32 + ach8 * 4;
        const float4 ga = *reinterpret_cast<const float4*>(cg + gk);
        const float4 be = *reinterpret_cast<const float4*>(cb + gk);
        bf16x4 o;
        o[0] = (__bf16)(ga.x * ((float)raw[0] - ams.x) * ams.y + be.x);
        o[1] = (__bf16)(ga.y * ((float)raw[1] - ams.x) * ams.y + be.y);
        o[2] = (__bf16)(ga.z * ((float)raw[2] - ams.x) * ams.y + be.z);
        o[3] = (__bf16)(ga.w * ((float)raw[3] - ams.x) * ams.y + be.w);
        return o;
    };
    const __bf16* w2b = wC2 + (long)t * Dc * IDp;
    auto stageB2 = [&](int nc, int kt, int buf) {
        #pragma unroll
        for (int rep = 0; rep < 2; rep++) {
            const int c = rep * 512 + tid;
            const int n = c >> 2, ch = c & 3;
            const int gk = kt * 32 + ((ch ^ ((n >> 1) & 3)) << 3);
            gload16(w2b + (long)(nc * 256 + n) * IDp + gk, sbuf[buf] + c * 16);
        }
    };

    f32x4 acc[2][4];
    #pragma unroll
    for (int i = 0; i < 2; i++)
        #pragma unroll
        for (int j = 0; j < 4; j++)
            acc[i][j] = (f32x4){0.f, 0.f, 0.f, 0.f};

    {
        bf16x4 a0 = loadA(0);
        stageB1(0, 0);
        writeA(xformA(a0, 0), 0);
        __syncthreads();
        for (int kt = 0; kt < 24; kt++) {
            const int buf = kt & 1;
            bf16x4 anx;
            if (kt < 23) { anx = loadA(kt + 1); stageB1(kt + 1, buf ^ 1); }
            const char* Abase = sbuf[buf];
            const char* Bbase = sbuf[buf] + 4096;
            bf16x8 af[2], bfr[4];
            #pragma unroll
            for (int i = 0; i < 2; i++) {
                const int row = wm + i * 16 + l15;
                af[i] = *reinterpret_cast<const bf16x8*>(
                    Abase + row * 64 + ((l4 ^ ((row >> 1) & 3)) << 4));
            }
            #pragma unroll
            for (int j = 0; j < 4; j++) {
                const int row = wn + j * 16 + l15;
                bfr[j] = *reinterpret_cast<const bf16x8*>(
                    Bbase + row * 64 + ((l4 ^ ((row >> 1) & 3)) << 4));
            }
            #pragma unroll
            for (int i = 0; i < 2; i++)
                #pragma unroll
                for (int j = 0; j < 4; j++)
                    acc[i][j] = __builtin_amdgcn_mfma_f32_16x16x32_bf16(af[i], bfr[j], acc[i][j], 0, 0, 0);
            if (kt < 23) writeA(xformA(anx, kt + 1), buf ^ 1);
            __syncthreads();
        }
    }

    // prefetch first stage-2 B tile (overlaps the G-write epilogue)
    stageB2(0, 0, 0);

    // stage-1 epilogue: gelu -> G ([m][k] swizzled, phys = chunk ^ (m&7))
    #pragma unroll
    for (int i = 0; i < 2; i++) {
        #pragma unroll
        for (int j = 0; j < 4; j++) {
            const int k = wn + j * 16 + l15;
            #pragma unroll
            for (int r = 0; r < 4; r++) {
                const int m = wm + i * 16 + l4 * 4 + r;
                const float v = gelu_f(acc[i][j][r]);
                const int phys = (k >> 3) ^ (m & 7);
                G[m * 256 + phys * 8 + (k & 7)] =
                    __builtin_bit_cast(unsigned short, (__bf16)v);
            }
        }
    }
    __syncthreads();

    // ---- stage 2: out = x1 + G @ wC2^T, 3 n-passes of 256, K=256, BK=32 ----
    float* ob = out + ((long)b * Sc + m0) * Dc;
    for (int nc = 0; nc < 3; nc++) {
        f32x4 a2[2][4];
        #pragma unroll
        for (int i = 0; i < 2; i++)
            #pragma unroll
            for (int j = 0; j < 4; j++)
                a2[i][j] = (f32x4){0.f, 0.f, 0.f, 0.f};

        // T14: residual loads issued now, consumed in the epilogue
        float res[2][4][4];
        #pragma unroll
        for (int i = 0; i < 2; i++)
            #pragma unroll
            for (int j = 0; j < 4; j++) {
                const int gn = nc * 256 + wn + j * 16 + l15;
                #pragma unroll
                for (int r = 0; r < 4; r++) {
                    const int gm = wm + i * 16 + l4 * 4 + r;
                    res[i][j][r] = (float)xb[(long)gm * Dc + gn];
                }
            }

        for (int kt = 0; kt < 8; kt++) {
            const int buf = kt & 1;
            if (kt < 7)       stageB2(nc, kt + 1, buf ^ 1);
            else if (nc < 2)  stageB2(nc + 1, 0, buf ^ 1);
            bf16x8 af[2], bfr[4];
            #pragma unroll
            for (int i = 0; i < 2; i++) {
                const int row = wm + i * 16 + l15;
                const int phys = (kt * 4 + l4) ^ (row & 7);
                af[i] = *reinterpret_cast<const bf16x8*>(
                    (const char*)G + row * 512 + phys * 16);
            }
            #pragma unroll
            for (int j = 0; j < 4; j++) {
                const int row = wn + j * 16 + l15;
                bfr[j] = *reinterpret_cast<const bf16x8*>(
                    sbuf[buf] + row * 64 + ((l4 ^ ((row >> 1) & 3)) << 4));
            }
            #pragma unroll
            for (int i = 0; i < 2; i++)
                #pragma unroll
                for (int j = 0; j < 4; j++)
                    a2[i][j] = __builtin_amdgcn_mfma_f32_16x16x32_bf16(af[i], bfr[j], a2[i][j], 0, 0, 0);
            __syncthreads();
        }
        #pragma unroll
        for (int i = 0; i < 2; i++) {
            #pragma unroll
            for (int j = 0; j < 4; j++) {
                const int gn = nc * 256 + wn + j * 16 + l15;
                #pragma unroll
                for (int r = 0; r < 4; r++) {
                    const int gm = wm + i * 16 + l4 * 4 + r;
                    ob[(long)gm * Dc + gn] = a2[i][j][r] + res[i][j][r];
                }
            }
        }
    }
}

extern "C" void kernel_launch(void* const* d_in, const int* in_sizes, int n_in,
                              void* d_out, int out_size, void* d_ws, size_t ws_size,
                              hipStream_t stream) {
    const float* x      = (const float*)d_in[0];
    const int*   tasks  = (const int*)  d_in[1];
    const float* cln1   = (const float*)d_in[2];
    const float* cln2   = (const float*)d_in[3];
    const float* w1_tok = (const float*)d_in[4];
    const float* w2_tok = (const float*)d_in[5];
    const float* w1_ch  = (const float*)d_in[6];
    const float* w2_ch  = (const float*)d_in[7];
    float* out = (float*)d_out;

    char* ws = (char*)d_ws;
    const long oT1 = 0;
    const long oT2 = oT1 + (long)10 * ISp * Sc * 2;
    const long oC1 = oT2 + (long)10 * Sc * ISp * 2;
    const long oC2 = oC1 + (long)10 * IDp * Dc * 2;
    const long oA  = oC2 + (long)10 * Dc * IDp * 2;
    const long oG  = oA  + (long)Bc * Dc * Sc * 2;
    __bf16* wT1  = (__bf16*)(ws + oT1);
    __bf16* wT2  = (__bf16*)(ws + oT2);
    __bf16* wC1  = (__bf16*)(ws + oC1);
    __bf16* wC2  = (__bf16*)(ws + oC2);
    __bf16* h1T  = (__bf16*)(ws + oA);
    __bf16* x1   = (__bf16*)(ws + oA);     // reuses h1T (dead after GEMM2)
    __bf16* gbf  = (__bf16*)(ws + oG);

    // 0+1) fused: weight conversions + LN1-transpose (independent work)
    front_k<<<CVT_BLK + LN1_BLK, 256, 0, stream>>>(
        w1_tok, w2_tok, w1_ch, w2_ch, wT1, wT2, wC1, wC2,
        x, tasks, cln1, h1T);

    // GT = gelu(h1T @ W1tok[t]^T)   M=768, N=384, K=1024
    gemm_tn<1, 0, 0, 0><<<dim3(ISp / 128, Dc / 128, Bc), 512, 0, stream>>>(
        h1T, (long)Dc * Sc, Sc,
        wT1, (long)ISp * Sc, Sc,
        nullptr, 0,
        gbf, (long)Dc * ISp, ISp,
        tasks, Dc, ISp, Sc);

    // x1 = x + W2tok[t] @ GT^T   M=1024, N=768, K=384
    gemm_tn<0, 1, 0, 1><<<dim3(Dc / 128, Sc / 128, Bc), 512, 0, stream>>>(
        wT2, (long)Sc * ISp, ISp,
        gbf, (long)Dc * ISp, ISp,
        x, (long)Sc * Dc,
        x1, (long)Sc * Dc, Dc,
        tasks, Sc, Dc, ISp);

    // out = x1 + gelu(LN2(x1) @ W1ch^T) @ W2ch^T   (fused, 64-row x 512-thread)
    mlp_ch<<<(Sc / 64) * Bc, 512, 0, stream>>>(x1, tasks, cln2, wC1, wC2, out);
}

// Round 23
// 382.812 us; speedup vs baseline: 1.0757x; 1.0560x over previous
//
#include <hip/hip_runtime.h>
#include <math.h>

typedef __bf16 bf16x8 __attribute__((ext_vector_type(8)));
typedef __bf16 bf16x4 __attribute__((ext_vector_type(4)));
typedef float  f32x4  __attribute__((ext_vector_type(4)));

constexpr int Bc = 64, Sc = 1024, Dc = 768;
constexpr int ISc = 307, IDc = 230;
constexpr int ISp = 384, IDp = 256;   // padded: every GEMM M,N %128==0, K %64==0

static __device__ __forceinline__ float bf2f(unsigned short u) {
    return __builtin_bit_cast(float, (unsigned)u << 16);
}
// tanh-form GELU via exp2/rcp (trans pipe); |delta| vs erf-gelu ~3e-3 (safe).
static __device__ __forceinline__ float gelu_f(float v) {
    const float y = v * (0.7978845608f + 0.0356774081f * v * v);
    const float e = __builtin_amdgcn_exp2f(y * 2.8853900818f);
    return v * e * __builtin_amdgcn_rcpf(e + 1.0f);
}

// async global->LDS, 16B/lane, linear LDS dest (wave-uniform base + lane*16)
static __device__ __forceinline__ void gload16(const void* g, void* l) {
    __builtin_amdgcn_global_load_lds(
        (const __attribute__((address_space(1))) void*)g,
        (__attribute__((address_space(3))) void*)l, 16, 0, 0);
}

// ---------------- fused front kernel: weight cvt + LN1-transpose + u/v ----
constexpr int CH0 = 10 * ISp * (Sc  / 8);
constexpr int CH1 = 10 * Sc  * (ISp / 8);
constexpr int CH2 = 10 * IDp * (Dc  / 8);
constexpr int CH3 = 10 * Dc  * (IDp / 8);
constexpr int CB0 = CH0, CB1 = CB0 + CH1, CB2 = CB1 + CH2, CB3 = CB2 + CH3;
constexpr int CVT_BLK = CB3 / 256;          // 5760 exactly
constexpr int LN1_BLK = (Sc / 32) * Bc;     // 2048
constexpr int UV_BLK  = (10 * 256) / 4;     // 640 (4 waves/block, 1 (t,n)/wave)

__device__ __forceinline__ void cvt_one(
    const float* __restrict__ in, __bf16* __restrict__ out,
    int inrows, int outrows, int incols, int outcols, int c)
{
    const int cpr  = outcols >> 3;
    const int perT = outrows * cpr;
    const int t    = c / perT;
    const int rem  = c - t * perT;
    const int r    = rem / cpr;
    const int cc   = (rem - r * cpr) * 8;
    bf16x8 o;
    if (r < inrows) {
        const float* src = in + ((long)t * inrows + r) * incols + cc;
        #pragma unroll
        for (int e = 0; e < 8; e++)
            o[e] = (cc + e < incols) ? (__bf16)src[e] : (__bf16)0.0f;
    } else {
        #pragma unroll
        for (int e = 0; e < 8; e++) o[e] = (__bf16)0.0f;
    }
    *reinterpret_cast<bf16x8*>(out + ((long)t * outrows + r) * outcols + cc) = o;
}

__global__ __launch_bounds__(256) void front_k(
    const float* __restrict__ w1t, const float* __restrict__ w2t,
    const float* __restrict__ w1c, const float* __restrict__ w2c,
    __bf16* __restrict__ o1t, __bf16* __restrict__ o2t,
    __bf16* __restrict__ o1c, __bf16* __restrict__ o2c,
    const float* __restrict__ x, const int* __restrict__ tasks,
    const float* __restrict__ cln1, const float* __restrict__ cln2,
    __bf16* __restrict__ h1T,
    float* __restrict__ uvu, float* __restrict__ uvv)
{
    constexpr int RPB = 32, LDT = Dc + 8;
    __shared__ unsigned short T[RPB * LDT];        // 48.5 KB (ln1 part only)
    const int bid = blockIdx.x;
    if (bid < CVT_BLK) {
        const int c = bid * 256 + threadIdx.x;
        if (c < CB0)      cvt_one(w1t, o1t, ISc, ISp, Sc,  Sc,  c);
        else if (c < CB1) cvt_one(w2t, o2t, Sc,  Sc,  ISc, ISp, c - CB0);
        else if (c < CB2) {
            // w1_ch -> wC1 with gamma folded: out[t][r][d] = w1c*gamma_t[d]
            const int c2  = c - CB1;
            const int cpr = Dc >> 3;
            const int perT = IDp * cpr;
            const int t   = c2 / perT;
            const int rem = c2 - t * perT;
            const int r   = rem / cpr;
            const int cc  = (rem - r * cpr) * 8;
            bf16x8 o;
            if (r < IDc) {
                const float* src = w1c + ((long)t * IDc + r) * Dc + cc;
                const float* gsr = cln2 + (long)t * 2 * Dc + cc;
                #pragma unroll
                for (int e = 0; e < 8; e++)
                    o[e] = (__bf16)(src[e] * gsr[e]);
            } else {
                #pragma unroll
                for (int e = 0; e < 8; e++) o[e] = (__bf16)0.0f;
            }
            *reinterpret_cast<bf16x8*>(o1c + ((long)t * IDp + r) * Dc + cc) = o;
        }
        else              cvt_one(w2c, o2c, Dc,  Dc,  IDc, IDp, c - CB2);
        return;
    }
    if (bid < CVT_BLK + LN1_BLK) {
        const int idx = bid - CVT_BLK;
        const int b   = idx >> 5;
        const int s0  = (idx & 31) * RPB;
        const int t   = tasks[b];
        const int tid = threadIdx.x;
        const int wv  = tid >> 6;
        const int l   = tid & 63;

        const float4* Ga = reinterpret_cast<const float4*>(cln1 + (long)t * 2 * Dc);
        const float4* Be = reinterpret_cast<const float4*>(cln1 + (long)t * 2 * Dc + Dc);
        const float4 g0 = Ga[l], g1 = Ga[l + 64], g2 = Ga[l + 128];
        const float4 b0 = Be[l], b1 = Be[l + 64], b2 = Be[l + 128];

        #pragma unroll
        for (int rr = 0; rr < 8; rr++) {
            const int r = wv * 8 + rr;
            const float4* xr = reinterpret_cast<const float4*>(x + ((long)b * Sc + s0 + r) * Dc);
            const float4 v0 = xr[l], v1 = xr[l + 64], v2 = xr[l + 128];
            float s = v0.x + v0.y + v0.z + v0.w + v1.x + v1.y + v1.z + v1.w
                    + v2.x + v2.y + v2.z + v2.w;
            float q = v0.x*v0.x + v0.y*v0.y + v0.z*v0.z + v0.w*v0.w
                    + v1.x*v1.x + v1.y*v1.y + v1.z*v1.z + v1.w*v1.w
                    + v2.x*v2.x + v2.y*v2.y + v2.z*v2.z + v2.w*v2.w;
            #pragma unroll
            for (int o = 1; o < 64; o <<= 1) { s += __shfl_xor(s, o); q += __shfl_xor(q, o); }
            const float mu   = s * (1.0f / Dc);
            const float var  = fmaxf(q * (1.0f / Dc) - mu * mu, 0.0f);
            const float rstd = 1.0f / sqrtf(var + 1e-5f);
            unsigned short* tr = &T[r * LDT];
            bf16x4 o0, o1, o2;
            o0[0] = (__bf16)(g0.x * ((v0.x - mu) * rstd) + b0.x);
            o0[1] = (__bf16)(g0.y * ((v0.y - mu) * rstd) + b0.y);
            o0[2] = (__bf16)(g0.z * ((v0.z - mu) * rstd) + b0.z);
            o0[3] = (__bf16)(g0.w * ((v0.w - mu) * rstd) + b0.w);
            o1[0] = (__bf16)(g1.x * ((v1.x - mu) * rstd) + b1.x);
            o1[1] = (__bf16)(g1.y * ((v1.y - mu) * rstd) + b1.y);
            o1[2] = (__bf16)(g1.z * ((v1.z - mu) * rstd) + b1.z);
            o1[3] = (__bf16)(g1.w * ((v1.w - mu) * rstd) + b1.w);
            o2[0] = (__bf16)(g2.x * ((v2.x - mu) * rstd) + b2.x);
            o2[1] = (__bf16)(g2.y * ((v2.y - mu) * rstd) + b2.y);
            o2[2] = (__bf16)(g2.z * ((v2.z - mu) * rstd) + b2.z);
            o2[3] = (__bf16)(g2.w * ((v2.w - mu) * rstd) + b2.w);
            *reinterpret_cast<bf16x4*>(&tr[l * 4])        = o0;
            *reinterpret_cast<bf16x4*>(&tr[256 + l * 4])  = o1;
            *reinterpret_cast<bf16x4*>(&tr[512 + l * 4])  = o2;
        }
        __syncthreads();
        #pragma unroll
        for (int c = 0; c < 3; c++) {
            const int d = threadIdx.x + c * 256;
            unsigned short tmp[32];
            #pragma unroll
            for (int e = 0; e < 32; e++) tmp[e] = T[e * LDT + d];
            __bf16* dst = h1T + ((long)b * Dc + d) * Sc + s0;
            #pragma unroll
            for (int u = 0; u < 4; u++)
                reinterpret_cast<uint4*>(dst)[u] = reinterpret_cast<const uint4*>(tmp)[u];
        }
        return;
    }
    // ---- u/v pass: u[t][n] = sum_d gamma_t[d]*W1ch[t,n,d]; v likewise beta
    const int p = (bid - CVT_BLK - LN1_BLK) * 4 + (threadIdx.x >> 6);  // 0..2559
    const int t = p >> 8, n = p & 255;
    const int l = threadIdx.x & 63;
    float su = 0.f, sv = 0.f;
    if (n < IDc) {
        const float* wr = w1c + ((long)t * IDc + n) * Dc + l * 12;
        const float* gr = cln2 + (long)t * 2 * Dc + l * 12;
        const float* br = gr + Dc;
        #pragma unroll
        for (int e = 0; e < 12; e++) {
            const float w = wr[e];
            su += gr[e] * w;
            sv += br[e] * w;
        }
    }
    #pragma unroll
    for (int o = 1; o < 64; o <<= 1) { su += __shfl_xor(su, o); sv += __shfl_xor(sv, o); }
    if (l == 0) { uvu[t * 256 + n] = su; uvv[t * 256 + n] = sv; }
}

// ---------------- bf16 TN MFMA GEMM: 512 threads, 8 waves (4m x 2n) --------
template<int DOGELU, int RESM, int OUTF32, int ATASK>
__global__ __launch_bounds__(512, 4) void gemm_tn(
    const __bf16* __restrict__ A, long sA, int lda,
    const __bf16* __restrict__ B, long sB, int ldb,
    const void* __restrict__ R, long sR,
    void* __restrict__ C, long sC, int ldc,
    const int* __restrict__ tasks, int M, int N, int K)
{
    constexpr int BM = 128, BN = 128, BK = 64;
    constexpr int BUFB = 32768;
    __shared__ uint4 lds4[2 * BUFB / 16];       // 64 KB
    char* lbase = (char*)lds4;

    const int gx  = gridDim.x, gy = gridDim.y;
    const int tpb = gx * gy;
    const long lin = blockIdx.x + (long)gx * (blockIdx.y + (long)gy * blockIdx.z);
    const int  xcd  = (int)(lin & 7);
    const long idx  = lin >> 3;
    const int  lb   = (int)(idx / tpb);
    const int  tile = (int)(idx - (long)lb * tpb);
    const int  b    = xcd * 8 + lb;
    const int  m0   = (tile / gx) * BM;
    const int  n0   = (tile % gx) * BN;

    const int t = tasks[b];
    const __bf16* Ab = A + (ATASK ? (long)t : (long)b) * sA;
    const __bf16* Bb = B + (ATASK ? (long)b : (long)t) * sB;
    const int tid = threadIdx.x, lane = tid & 63, wid = tid >> 6;
    const int wm = (wid >> 1) * 32, wn = (wid & 1) * 64;   // 4m x 2n
    const int l15 = lane & 15, l4 = lane >> 4;

    f32x4 acc[2][4];
    #pragma unroll
    for (int i = 0; i < 2; i++)
        #pragma unroll
        for (int j = 0; j < 4; j++)
            acc[i][j] = (f32x4){0.f, 0.f, 0.f, 0.f};

    auto STAGE = [&](int k0, int buf) {
        char* dst = lbase + buf * BUFB;
        #pragma unroll
        for (int rep = 0; rep < 2; rep++) {
            const int c = rep * 512 + tid;
            const int m = c >> 3, ch = c & 7;
            const int gk = k0 + ((ch ^ (m & 7)) << 3);
            gload16(Ab + (long)(m0 + m) * lda + gk, dst + c * 16);
        }
        #pragma unroll
        for (int rep = 0; rep < 2; rep++) {
            const int c = rep * 512 + tid;
            const int n = c >> 3, ch = c & 7;
            const int gk = k0 + ((ch ^ (n & 7)) << 3);
            gload16(Bb + (long)(n0 + n) * ldb + gk, dst + 16384 + c * 16);
        }
    };

    const int nt = K / BK;
    STAGE(0, 0);
    __syncthreads();
    int cur = 0;
    for (int tt = 0; tt < nt; tt++) {
        if (tt + 1 < nt) STAGE((tt + 1) * BK, cur ^ 1);
        const char* bb = lbase + cur * BUFB;
        #pragma unroll
        for (int h = 0; h < 2; h++) {
            bf16x8 af[2], bfr[4];
            #pragma unroll
            for (int i = 0; i < 2; i++) {
                const int row = wm + i * 16 + l15;
                af[i] = *reinterpret_cast<const bf16x8*>(
                    bb + row * 128 + (((h * 4 + l4) ^ (row & 7)) << 4));
            }
            #pragma unroll
            for (int j = 0; j < 4; j++) {
                const int row = wn + j * 16 + l15;
                bfr[j] = *reinterpret_cast<const bf16x8*>(
                    bb + 16384 + row * 128 + (((h * 4 + l4) ^ (row & 7)) << 4));
            }
            #pragma unroll
            for (int i = 0; i < 2; i++)
                #pragma unroll
                for (int j = 0; j < 4; j++)
                    acc[i][j] = __builtin_amdgcn_mfma_f32_16x16x32_bf16(af[i], bfr[j], acc[i][j], 0, 0, 0);
        }
        __syncthreads();
        cur ^= 1;
    }

    float*  Cf = (float*)C  + (long)b * sC;
    __bf16* Ch = (__bf16*)C + (long)b * sC;
    const float*  Rf = (RESM == 1) ? ((const float*)R  + (long)b * sR) : nullptr;
    const __bf16* Rh = (RESM == 2) ? ((const __bf16*)R + (long)b * sR) : nullptr;

    #pragma unroll
    for (int i = 0; i < 2; i++) {
        #pragma unroll
        for (int j = 0; j < 4; j++) {
            const int gn = n0 + wn + j * 16 + l15;
            #pragma unroll
            for (int r = 0; r < 4; r++) {
                const int gm = m0 + wm + i * 16 + l4 * 4 + r;
                float v = acc[i][j][r];
                if (DOGELU) v = gelu_f(v);
                if (RESM == 1) v += Rf[(long)gm * ldc + gn];
                if (RESM == 2) v += (float)Rh[(long)gm * ldc + gn];
                if (OUTF32) Cf[(long)gm * ldc + gn] = v;
                else        Ch[(long)gm * ldc + gn] = (__bf16)v;
            }
        }
    }
}

// ---------------- fused channel-MLP with algebraic LN2 hoist --------------
// out = x1 + gelu(LN2(x1)@W1^T)@W2^T, where LN2 commutes with the GEMM:
//   LN2(x)@W1^T = rstd*(x@(gamma.W1)^T) - rstd*mu*u + v   (u,v per task)
// wC1 arrives gamma-folded; stage-1 A is raw x1 staged via global_load_lds
// (no per-phase LN VALU, no reg round-trip). Stats applied only in epilogue.
__global__ __launch_bounds__(512, 4) void mlp_ch(
    const __bf16* __restrict__ x1, const int* __restrict__ tasks,
    const float* __restrict__ uvu, const float* __restrict__ uvv,
    const __bf16* __restrict__ wC1,   // [10][IDp][Dc] gamma-folded, k-contig
    const __bf16* __restrict__ wC2,   // [10][Dc][IDp] k-contig
    float* __restrict__ out)
{
    __shared__ float2 st[64];
    __shared__ unsigned short G[64 * 256];     // 32 KB
    __shared__ char sbuf[2][20480];            // 40 KB

    const int lin = blockIdx.x;
    const int xcd = lin & 7;
    const int idx = lin >> 3;                  // 0..127
    const int b   = xcd * 8 + (idx >> 4);
    const int m0  = (idx & 15) * 64;
    const int t   = tasks[b];

    const int tid = threadIdx.x;
    const int wid = tid >> 6, lane = tid & 63;
    const int wm  = (wid >> 2) * 32, wn = (wid & 3) * 64;   // 2m x 4n
    const int l15 = lane & 15, l4 = lane >> 4;

    const __bf16* xb = x1 + ((long)b * Sc + m0) * Dc;

    // ---- LN2 stats (mu, rstd) per row; also pre-warms L2 for A gloads ----
    #pragma unroll 2
    for (int rr = 0; rr < 8; rr++) {
        const int m = wid * 8 + rr;
        const ushort4* xr = reinterpret_cast<const ushort4*>(xb + (long)m * Dc);
        const ushort4 u0 = xr[lane], u1 = xr[lane + 64], u2 = xr[lane + 128];
        float s = 0.f, q = 0.f, v;
        v = bf2f(u0.x); s += v; q += v*v;  v = bf2f(u0.y); s += v; q += v*v;
        v = bf2f(u0.z); s += v; q += v*v;  v = bf2f(u0.w); s += v; q += v*v;
        v = bf2f(u1.x); s += v; q += v*v;  v = bf2f(u1.y); s += v; q += v*v;
        v = bf2f(u1.z); s += v; q += v*v;  v = bf2f(u1.w); s += v; q += v*v;
        v = bf2f(u2.x); s += v; q += v*v;  v = bf2f(u2.y); s += v; q += v*v;
        v = bf2f(u2.z); s += v; q += v*v;  v = bf2f(u2.w); s += v; q += v*v;
        #pragma unroll
        for (int o = 1; o < 64; o <<= 1) { s += __shfl_xor(s, o); q += __shfl_xor(q, o); }
        if (lane == 0) {
            const float mu  = s * (1.0f / Dc);
            const float var = fmaxf(q * (1.0f / Dc) - mu * mu, 0.0f);
            st[m] = make_float2(mu, 1.0f / sqrtf(var + 1e-5f));
        }
    }
    __syncthreads();

    // ---- stage 1: acc = x1_tile @ wC1g^T (raw A), K=768, BK=32 ----
    // sbuf layout per buffer: A [0,4096) rows 64x64B, B [4096,20480) 256x64B;
    // both with involution f(r)=(r>>1)&3 on 16B chunks (proven conflict-free).
    auto stageA = [&](int kt, int buf) {
        if (tid < 256) {
            const int m = tid >> 2, ch = tid & 3;
            const int gk = kt * 32 + ((ch ^ ((m >> 1) & 3)) << 3);
            gload16(xb + (long)m * Dc + gk, sbuf[buf] + tid * 16);
        }
    };
    auto stageB1 = [&](int kt, int buf) {
        #pragma unroll
        for (int rep = 0; rep < 2; rep++) {
            const int c = rep * 512 + tid;
            const int n = c >> 2, ch = c & 3;
            const int gk = kt * 32 + ((ch ^ ((n >> 1) & 3)) << 3);
            gload16(wC1 + ((long)t * IDp + n) * Dc + gk, sbuf[buf] + 4096 + c * 16);
        }
    };
    const __bf16* w2b = wC2 + (long)t * Dc * IDp;
    auto stageB2 = [&](int nc, int kt, int buf) {
        #pragma unroll
        for (int rep = 0; rep < 2; rep++) {
            const int c = rep * 512 + tid;
            const int n = c >> 2, ch = c & 3;
            const int gk = kt * 32 + ((ch ^ ((n >> 1) & 3)) << 3);
            gload16(w2b + (long)(nc * 256 + n) * IDp + gk, sbuf[buf] + c * 16);
        }
    };

    f32x4 acc[2][4];
    #pragma unroll
    for (int i = 0; i < 2; i++)
        #pragma unroll
        for (int j = 0; j < 4; j++)
            acc[i][j] = (f32x4){0.f, 0.f, 0.f, 0.f};

    stageA(0, 0);
    stageB1(0, 0);
    __syncthreads();
    for (int kt = 0; kt < 24; kt++) {
        const int buf = kt & 1;
        if (kt < 23) { stageA(kt + 1, buf ^ 1); stageB1(kt + 1, buf ^ 1); }
        const char* Abase = sbuf[buf];
        const char* Bbase = sbuf[buf] + 4096;
        bf16x8 af[2], bfr[4];
        #pragma unroll
        for (int i = 0; i < 2; i++) {
            const int row = wm + i * 16 + l15;
            af[i] = *reinterpret_cast<const bf16x8*>(
                Abase + row * 64 + ((l4 ^ ((row >> 1) & 3)) << 4));
        }
        #pragma unroll
        for (int j = 0; j < 4; j++) {
            const int row = wn + j * 16 + l15;
            bfr[j] = *reinterpret_cast<const bf16x8*>(
                Bbase + row * 64 + ((l4 ^ ((row >> 1) & 3)) << 4));
        }
        #pragma unroll
        for (int i = 0; i < 2; i++)
            #pragma unroll
            for (int j = 0; j < 4; j++)
                acc[i][j] = __builtin_amdgcn_mfma_f32_16x16x32_bf16(af[i], bfr[j], acc[i][j], 0, 0, 0);
        __syncthreads();
    }

    // prefetch first stage-2 B tile (overlaps the epilogue)
    stageB2(0, 0, 0);

    // stage-1 epilogue: G = gelu(rstd*acc - rstd*mu*u[n] + v[n])
    float uu[4], vv[4];
    #pragma unroll
    for (int j = 0; j < 4; j++) {
        const int gn = wn + j * 16 + l15;
        uu[j] = uvu[t * 256 + gn];
        vv[j] = uvv[t * 256 + gn];
    }
    #pragma unroll
    for (int i = 0; i < 2; i++) {
        #pragma unroll
        for (int r = 0; r < 4; r++) {
            const int m = wm + i * 16 + l4 * 4 + r;
            const float2 smr = st[m];
            const float rs = smr.y, rmu = smr.y * smr.x;
            #pragma unroll
            for (int j = 0; j < 4; j++) {
                const int k = wn + j * 16 + l15;
                const float pre = rs * acc[i][j][r] - rmu * uu[j] + vv[j];
                const float v = gelu_f(pre);
                const int phys = (k >> 3) ^ (m & 7);
                G[m * 256 + phys * 8 + (k & 7)] =
                    __builtin_bit_cast(unsigned short, (__bf16)v);
            }
        }
    }
    __syncthreads();

    // ---- stage 2: out = x1 + G @ wC2^T, 3 n-passes of 256, K=256, BK=32 ----
    float* ob = out + ((long)b * Sc + m0) * Dc;
    for (int nc = 0; nc < 3; nc++) {
        f32x4 a2[2][4];
        #pragma unroll
        for (int i = 0; i < 2; i++)
            #pragma unroll
            for (int j = 0; j < 4; j++)
                a2[i][j] = (f32x4){0.f, 0.f, 0.f, 0.f};

        // T14: residual loads issued now, consumed in the epilogue
        float res[2][4][4];
        #pragma unroll
        for (int i = 0; i < 2; i++)
            #pragma unroll
            for (int j = 0; j < 4; j++) {
                const int gn = nc * 256 + wn + j * 16 + l15;
                #pragma unroll
                for (int r = 0; r < 4; r++) {
                    const int gm = wm + i * 16 + l4 * 4 + r;
                    res[i][j][r] = (float)xb[(long)gm * Dc + gn];
                }
            }

        for (int kt = 0; kt < 8; kt++) {
            const int buf = kt & 1;
            if (kt < 7)       stageB2(nc, kt + 1, buf ^ 1);
            else if (nc < 2)  stageB2(nc + 1, 0, buf ^ 1);
            bf16x8 af[2], bfr[4];
            #pragma unroll
            for (int i = 0; i < 2; i++) {
                const int row = wm + i * 16 + l15;
                const int phys = (kt * 4 + l4) ^ (row & 7);
                af[i] = *reinterpret_cast<const bf16x8*>(
                    (const char*)G + row * 512 + phys * 16);
            }
            #pragma unroll
            for (int j = 0; j < 4; j++) {
                const int row = wn + j * 16 + l15;
                bfr[j] = *reinterpret_cast<const bf16x8*>(
                    sbuf[buf] + row * 64 + ((l4 ^ ((row >> 1) & 3)) << 4));
            }
            #pragma unroll
            for (int i = 0; i < 2; i++)
                #pragma unroll
                for (int j = 0; j < 4; j++)
                    a2[i][j] = __builtin_amdgcn_mfma_f32_16x16x32_bf16(af[i], bfr[j], a2[i][j], 0, 0, 0);
            __syncthreads();
        }
        #pragma unroll
        for (int i = 0; i < 2; i++) {
            #pragma unroll
            for (int j = 0; j < 4; j++) {
                const int gn = nc * 256 + wn + j * 16 + l15;
                #pragma unroll
                for (int r = 0; r < 4; r++) {
                    const int gm = wm + i * 16 + l4 * 4 + r;
                    ob[(long)gm * Dc + gn] = a2[i][j][r] + res[i][j][r];
                }
            }
        }
    }
}

extern "C" void kernel_launch(void* const* d_in, const int* in_sizes, int n_in,
                              void* d_out, int out_size, void* d_ws, size_t ws_size,
                              hipStream_t stream) {
    const float* x      = (const float*)d_in[0];
    const int*   tasks  = (const int*)  d_in[1];
    const float* cln1   = (const float*)d_in[2];
    const float* cln2   = (const float*)d_in[3];
    const float* w1_tok = (const float*)d_in[4];
    const float* w2_tok = (const float*)d_in[5];
    const float* w1_ch  = (const float*)d_in[6];
    const float* w2_ch  = (const float*)d_in[7];
    float* out = (float*)d_out;

    char* ws = (char*)d_ws;
    const long oT1 = 0;
    const long oT2 = oT1 + (long)10 * ISp * Sc * 2;
    const long oC1 = oT2 + (long)10 * Sc * ISp * 2;
    const long oC2 = oC1 + (long)10 * IDp * Dc * 2;
    const long oU  = oC2 + (long)10 * Dc * IDp * 2;   // u: 10*256 f32
    const long oV  = oU  + (long)10 * 256 * 4;        // v: 10*256 f32
    const long oA  = oV  + (long)10 * 256 * 4;
    const long oG  = oA  + (long)Bc * Dc * Sc * 2;
    __bf16* wT1  = (__bf16*)(ws + oT1);
    __bf16* wT2  = (__bf16*)(ws + oT2);
    __bf16* wC1  = (__bf16*)(ws + oC1);
    __bf16* wC2  = (__bf16*)(ws + oC2);
    float*  uvu  = (float*)(ws + oU);
    float*  uvv  = (float*)(ws + oV);
    __bf16* h1T  = (__bf16*)(ws + oA);
    __bf16* x1   = (__bf16*)(ws + oA);     // reuses h1T (dead after GEMM2)
    __bf16* gbf  = (__bf16*)(ws + oG);

    // 0+1+uv) fused: weight cvt (gamma-folded wC1) + LN1-transpose + u/v
    front_k<<<CVT_BLK + LN1_BLK + UV_BLK, 256, 0, stream>>>(
        w1_tok, w2_tok, w1_ch, w2_ch, wT1, wT2, wC1, wC2,
        x, tasks, cln1, cln2, h1T, uvu, uvv);

    // GT = gelu(h1T @ W1tok[t]^T)   M=768, N=384, K=1024
    gemm_tn<1, 0, 0, 0><<<dim3(ISp / 128, Dc / 128, Bc), 512, 0, stream>>>(
        h1T, (long)Dc * Sc, Sc,
        wT1, (long)ISp * Sc, Sc,
        nullptr, 0,
        gbf, (long)Dc * ISp, ISp,
        tasks, Dc, ISp, Sc);

    // x1 = x + W2tok[t] @ GT^T   M=1024, N=768, K=384
    gemm_tn<0, 1, 0, 1><<<dim3(Dc / 128, Sc / 128, Bc), 512, 0, stream>>>(
        wT2, (long)Sc * ISp, ISp,
        gbf, (long)Dc * ISp, ISp,
        x, (long)Sc * Dc,
        x1, (long)Sc * Dc, Dc,
        tasks, Sc, Dc, ISp);

    // out = x1 + gelu(LN2(x1) @ W1ch^T) @ W2ch^T   (fused, LN2 hoisted)
    mlp_ch<<<(Sc / 64) * Bc, 512, 0, stream>>>(x1, tasks, uvu, uvv, wC1, wC2, out);
}